// Round 8
// baseline (375.652 us; speedup 1.0000x reference)
//
#include <hip/hip_runtime.h>
#include <math.h>

// B=4, L=2048, D=1024, H=16, dh=64, M=8192, scale=0.125
// R14: attn KVBLK 64->128 with 16-slot LDS swizzle. Old layout had 128B rows
// (row contributes 0 to bank) + 3-bit XOR -> 32-row fragment reads pigeonhole
// into 8 slots = 4-way conflict (8.4e6 cycles). New: K packed [64][128]
// (key k -> row k&63, colbase (k>>6)*64), V [d][0..127]; 4-bit XOR
// ((row&15)<<3) -> 32 rows over 16 slots = 2-way = free. Barriers halve
// (64->32). setprio(1) wraps the compute phase (T5, attn-proven). Softmax
// pipeline (exp2 builtin, cvt_pk, permlane+s_nop, lacc-last) unchanged.

using f32x4 = __attribute__((ext_vector_type(4))) float;
using f32x16 = __attribute__((ext_vector_type(16))) float;
using bf16x8 = __attribute__((ext_vector_type(8))) short;

__device__ __forceinline__ unsigned short f2bf(float x) {
  union { float f; unsigned u; } v; v.f = x;
  unsigned r = v.u + 0x7fff + ((v.u >> 16) & 1);  // RNE
  return (unsigned short)(r >> 16);
}

__device__ __forceinline__ void g2l16(const void* g, void* l) {
  __builtin_amdgcn_global_load_lds(
      (const __attribute__((address_space(1))) unsigned int*)g,
      (__attribute__((address_space(3))) unsigned int*)l, 16, 0, 0);
}

// Transpose 4 weights in one launch: W[1024 k][1024 n] fp32 -> WT[n][k] bf16
__global__ __launch_bounds__(256) void wt4_k(const float* __restrict__ W0,
                                             const float* __restrict__ W1,
                                             const float* __restrict__ W2,
                                             const float* __restrict__ W3,
                                             short* __restrict__ WT) {
  __shared__ float t[64][65];
  const int z = blockIdx.z;
  const float* W = z == 0 ? W0 : (z == 1 ? W1 : (z == 2 ? W2 : W3));
  short* hiT = WT + (size_t)z * 1048576;
  const int n0 = blockIdx.x * 64, k0 = blockIdx.y * 64;
  const int tid = threadIdx.x;
  const int r = tid >> 4, c4 = (tid & 15) * 4;
#pragma unroll
  for (int i = 0; i < 4; i++) {
    const int row = r + i * 16;  // k
    const float4 v = *(const float4*)&W[(size_t)(k0 + row) * 1024 + n0 + c4];
    t[c4 + 0][row] = v.x;
    t[c4 + 1][row] = v.y;
    t[c4 + 2][row] = v.z;
    t[c4 + 3][row] = v.w;
  }
  __syncthreads();
#pragma unroll
  for (int i = 0; i < 4; i++) {
    const int row = r + i * 16;  // n
    short4 h;
    h.x = (short)f2bf(t[row][c4 + 0]);
    h.y = (short)f2bf(t[row][c4 + 1]);
    h.z = (short)f2bf(t[row][c4 + 2]);
    h.w = (short)f2bf(t[row][c4 + 3]);
    *(short4*)&hiT[(size_t)(n0 + row) * 1024 + k0 + c4] = h;
  }
}

// One-shot fp32 -> bf16 of the three input planes [8192][1024].
__global__ __launch_bounds__(256) void cvt3_k(const float* __restrict__ A0,
                                              const float* __restrict__ A1,
                                              const float* __restrict__ A2,
                                              short* __restrict__ X) {
  const int z = blockIdx.y;
  const float* A = z == 0 ? A0 : (z == 1 ? A1 : A2);
  short* Xo = X + (size_t)z * 8388608;
  const int t0 = blockIdx.x * 256 + threadIdx.x;
#pragma unroll 2
  for (int i = t0; i < 1048576; i += 262144) {
    const size_t o = (size_t)i * 8;
    const float4 a = *(const float4*)&A[o];
    const float4 b = *(const float4*)&A[o + 4];
    short tmp[8];
    tmp[0] = (short)f2bf(a.x);
    tmp[1] = (short)f2bf(a.y);
    tmp[2] = (short)f2bf(a.z);
    tmp[3] = (short)f2bf(a.w);
    tmp[4] = (short)f2bf(b.x);
    tmp[5] = (short)f2bf(b.y);
    tmp[6] = (short)f2bf(b.z);
    tmp[7] = (short)f2bf(b.w);
    *(bf16x8*)&Xo[o] = *(const bf16x8*)tmp;
  }
}

// z-batched projection GEMM: for z in {0,1,2}: C_z = X_z @ WT_z^T + b_z.
// BK=64, source-swizzled g2l16 staging (linear LDS dest, XOR'd global col).
// z=0: Q (x0.125/ln2 for exp2 softmax, bf16 BHLd)  z=1: K  z=2: V [B,H,64,L].
__global__ __launch_bounds__(256, 4) void proj3_k(
    const short* __restrict__ X, const short* __restrict__ WT,
    const float* __restrict__ b0, const float* __restrict__ b1,
    const float* __restrict__ b2, short* __restrict__ Obase) {
  __shared__ short smem[128 * 128];  // As[0..8192) Bs[8192..16384); epi reuse
  short* As = smem;
  short* Bs = smem + 8192;

  const int z = blockIdx.z;
  const short* A_g = X + (size_t)z * 8388608;
  const short* B_g = WT + (size_t)z * 1048576;
  const float* bias = z == 0 ? b0 : (z == 1 ? b1 : b2);
  short* outp = Obase + (size_t)z * 8388608;

  const int tid = threadIdx.x;
  const int lane = tid & 63;
  const int wave = tid >> 6;
  const int quad = lane >> 4;
  const int l16 = lane & 15;
  const int m0 = blockIdx.x * 128;
  const int n0 = blockIdx.y * 128;
  const int wm = (wave >> 1) * 64;
  const int wn = (wave & 1) * 64;

  const int srow = tid >> 3;       // 0..31 (+i*32): 32 rows per issue
  const int soff = (tid & 7) * 8;  // 16B granule within the 128B row

  f32x4 acc[4][4];
#pragma unroll
  for (int i = 0; i < 4; i++)
#pragma unroll
    for (int j = 0; j < 4; j++) acc[i][j] = f32x4{0.f, 0.f, 0.f, 0.f};

  for (int k0 = 0; k0 < 1024; k0 += 64) {
    __syncthreads();
#pragma unroll
    for (int i = 0; i < 4; i++) {
      const int row = srow + i * 32;
      const int osw = soff ^ ((row & 7) << 3);  // inverse-swizzled source col
      g2l16(&A_g[(size_t)(m0 + row) * 1024 + k0 + osw], &As[row * 64 + soff]);
      g2l16(&B_g[(size_t)(n0 + row) * 1024 + k0 + osw], &Bs[row * 64 + soff]);
    }
    __syncthreads();

#pragma unroll
    for (int ks = 0; ks < 2; ks++) {
      bf16x8 ah[4], bh[4];
#pragma unroll
      for (int t = 0; t < 4; t++) {
        const int ar = wm + t * 16 + l16;
        const int br = wn + t * 16 + l16;
        ah[t] = *(const bf16x8*)&As[ar * 64 + ((ks * 32 + quad * 8) ^ ((ar & 7) << 3))];
        bh[t] = *(const bf16x8*)&Bs[br * 64 + ((ks * 32 + quad * 8) ^ ((br & 7) << 3))];
      }
#pragma unroll
      for (int tm = 0; tm < 4; tm++)
#pragma unroll
        for (int tn = 0; tn < 4; tn++)
          acc[tm][tn] = __builtin_amdgcn_mfma_f32_16x16x32_bf16(ah[tm], bh[tn], acc[tm][tn], 0, 0, 0);
    }
  }

  float bz[4];
#pragma unroll
  for (int tn = 0; tn < 4; tn++) bz[tn] = bias[n0 + wn + tn * 16 + l16];
  // Q scale = 0.125 * (1/ln2) so attn can use exp2 directly
  const float sc = (z == 0) ? 0.18033688011112f : 1.0f;

  const int b = m0 >> 11;
  const int lbase = m0 & 2047;

  if (z == 2) {
    // V: [B,H,64,L] via LDS transpose (pad 144), b128 stores along L
#pragma unroll
    for (int half = 0; half < 2; half++) {
      __syncthreads();
      if ((wave & 1) == half) {
#pragma unroll
        for (int tm = 0; tm < 4; tm++)
#pragma unroll
          for (int tn = 0; tn < 4; tn++)
#pragma unroll
            for (int r = 0; r < 4; r++) {
              const int nl = tn * 16 + l16;                // d 0..63
              const int ml = wm + tm * 16 + quad * 4 + r;  // l 0..127
              smem[nl * 144 + ml] = (short)f2bf(acc[tm][tn][r] + bz[tn]);
            }
      }
      __syncthreads();
      const int h = (n0 >> 6) + half;
#pragma unroll
      for (int j = 0; j < 4; j++) {
        const int c = tid + j * 256;
        const int d = c >> 4;
        const int mo = (c & 15) * 8;
        *(bf16x8*)&outp[((size_t)((b * 16 + h) * 64 + d)) * 2048 + lbase + mo] =
            *(const bf16x8*)&smem[d * 144 + mo];
      }
    }
  } else {
    // Q/K: BHLd via LDS bounce (row-major m x 64d, pad 72), b128 stores along d
#pragma unroll
    for (int half = 0; half < 2; half++) {
      __syncthreads();
      if ((wave & 1) == half) {
#pragma unroll
        for (int tm = 0; tm < 4; tm++)
#pragma unroll
          for (int tn = 0; tn < 4; tn++)
#pragma unroll
            for (int r = 0; r < 4; r++) {
              const int ml = wm + tm * 16 + quad * 4 + r;  // 0..127
              const int nl = tn * 16 + l16;                // d 0..63
              smem[ml * 72 + nl] = (short)f2bf((acc[tm][tn][r] + bz[tn]) * sc);
            }
      }
      __syncthreads();
      const int h = (n0 >> 6) + half;
#pragma unroll
      for (int j = 0; j < 4; j++) {
        const int c = tid + j * 256;
        const int ml = c >> 3;          // 0..127
        const int off = (c & 7) * 8;    // 0..56
        *(bf16x8*)&outp[((size_t)(b * 16 + h) * 2048 + lbase + ml) * 64 + off] =
            *(const bf16x8*)&smem[ml * 72 + off];
      }
    }
  }
}

// Output projection: C[8192,1024] fp32 = ctx(bf16) @ WoT^T + bo.
// BK=64, source-swizzled g2l16 staging for both operands.
__global__ __launch_bounds__(256, 2) void outproj_k(
    const short* __restrict__ A_g, const short* __restrict__ B_g,
    const float* __restrict__ bias, float* __restrict__ out0) {
  __shared__ short As[8192];
  __shared__ short Bs[8192];

  const int tid = threadIdx.x;
  const int lane = tid & 63;
  const int wave = tid >> 6;
  const int quad = lane >> 4;
  const int l16 = lane & 15;
  const int m0 = blockIdx.x * 128;
  const int n0 = blockIdx.y * 128;
  const int wm = (wave >> 1) * 64;
  const int wn = (wave & 1) * 64;
  const int srow = tid >> 3;
  const int soff = (tid & 7) * 8;

  f32x4 acc[4][4];
#pragma unroll
  for (int i = 0; i < 4; i++)
#pragma unroll
    for (int j = 0; j < 4; j++) acc[i][j] = f32x4{0.f, 0.f, 0.f, 0.f};

  for (int k0 = 0; k0 < 1024; k0 += 64) {
    __syncthreads();
#pragma unroll
    for (int i = 0; i < 4; i++) {
      const int row = srow + i * 32;
      const int osw = soff ^ ((row & 7) << 3);
      g2l16(&A_g[(size_t)(m0 + row) * 1024 + k0 + osw], &As[row * 64 + soff]);
      g2l16(&B_g[(size_t)(n0 + row) * 1024 + k0 + osw], &Bs[row * 64 + soff]);
    }
    __syncthreads();

#pragma unroll
    for (int ks = 0; ks < 2; ks++) {
      bf16x8 ah[4], bh[4];
#pragma unroll
      for (int t = 0; t < 4; t++) {
        const int ar = wm + t * 16 + l16;
        const int br = wn + t * 16 + l16;
        ah[t] = *(const bf16x8*)&As[ar * 64 + ((ks * 32 + quad * 8) ^ ((ar & 7) << 3))];
        bh[t] = *(const bf16x8*)&Bs[br * 64 + ((ks * 32 + quad * 8) ^ ((br & 7) << 3))];
      }
#pragma unroll
      for (int tm = 0; tm < 4; tm++)
#pragma unroll
        for (int tn = 0; tn < 4; tn++)
          acc[tm][tn] = __builtin_amdgcn_mfma_f32_16x16x32_bf16(ah[tm], bh[tn], acc[tm][tn], 0, 0, 0);
    }
  }

  float bz[4];
#pragma unroll
  for (int tn = 0; tn < 4; tn++) bz[tn] = bias[n0 + wn + tn * 16 + l16];

#pragma unroll
  for (int tm = 0; tm < 4; tm++)
#pragma unroll
    for (int tn = 0; tn < 4; tn++) {
      const int n = n0 + wn + tn * 16 + l16;
#pragma unroll
      for (int r = 0; r < 4; r++) {
        const int m = m0 + wm + tm * 16 + quad * 4 + r;
        out0[(size_t)m * 1024 + n] = acc[tm][tn][r] + bz[tn];
      }
    }
}

// Flash attention, 32x32x16 MFMA, swapped QK^T, in-register softmax.
// KVBLK=128: K packed [64][128] (key k -> row k&63, colbase (k>>6)*64),
// V [d][key 0..127]; 4-bit XOR swizzle -> 2-way (free) fragment reads.
// Block = (b,h) x 128 Q rows (4 waves x 32). Grid (bh, qb): XCD-local K/V.
// Q pre-scaled by 0.125/ln2 -> raw v_exp_f32. Row sums on the MFMA pipe.
__global__ __launch_bounds__(256, 4) void attn5_k(const short* __restrict__ Qp,
                                                  const short* __restrict__ Kp,
                                                  const short* __restrict__ Vt,
                                                  short* __restrict__ Ctx) {
  __shared__ short Ks[64 * 128];
  __shared__ short Vs[64 * 128];

  const int tid = threadIdx.x;
  const int lane = tid & 63;
  const int wave = tid >> 6;
  const int l31 = lane & 31;
  const int hh = lane >> 5;        // wave half
  const int bh = blockIdx.x;       // XCD-local K/V
  const int q0 = blockIdx.y * 128;

  const short* Kb = Kp + (size_t)bh * 2048 * 64;
  const short* Vb = Vt + (size_t)bh * 64 * 2048;

  // Q fragments (B-operand: col q=l31, k-dim d = dseg*16 + hh*8 + e)
  bf16x8 qf[4];
#pragma unroll
  for (int dseg = 0; dseg < 4; dseg++)
    qf[dseg] = *(const bf16x8*)
        &Qp[((size_t)bh * 2048 + q0 + wave * 32 + l31) * 64 + dseg * 16 + hh * 8];

  bf16x8 ones;
#pragma unroll
  for (int j = 0; j < 8; j++) ones[j] = (short)0x3F80;

  f32x16 O[2], lacc;
#pragma unroll
  for (int t = 0; t < 2; t++)
#pragma unroll
    for (int r = 0; r < 16; r++) O[t][r] = 0.0f;
#pragma unroll
  for (int r = 0; r < 16; r++) lacc[r] = 0.0f;

  // staging: K granule = (key, 16B of d); V granule = (d, 16B of keys)
  const int kkey = tid >> 3;        // 0..31 (+i*32)
  const int kd   = (tid & 7) * 8;   // d col (shorts)
  const int vd   = tid >> 4;        // 0..15 (+i*16)
  const int vks  = (tid & 15) * 8;  // key col (shorts)

  bf16x8 kpre[4], vpre[4];
#pragma unroll
  for (int i = 0; i < 4; i++) {
    kpre[i] = *(const bf16x8*)&Kb[(size_t)(kkey + i * 32) * 64 + kd];
    vpre[i] = *(const bf16x8*)&Vb[(size_t)(vd + i * 16) * 2048 + vks];
  }

  for (int kt = 0; kt < 16; kt++) {
    __syncthreads();
#pragma unroll
    for (int i = 0; i < 4; i++) {
      const int key = kkey + i * 32;
      const int krow = key & 63;
      *(bf16x8*)&Ks[krow * 128 + ((((key >> 6) << 6) + kd) ^ ((krow & 15) << 3))] = kpre[i];
      const int d = vd + i * 16;
      *(bf16x8*)&Vs[d * 128 + (vks ^ ((d & 15) << 3))] = vpre[i];
    }
    __syncthreads();

    if (kt < 15) {  // prefetch next K/V tile (overlaps compute)
      const int nb = (kt + 1) * 128;
#pragma unroll
      for (int i = 0; i < 4; i++) {
        kpre[i] = *(const bf16x8*)&Kb[(size_t)(nb + kkey + i * 32) * 64 + kd];
        vpre[i] = *(const bf16x8*)&Vb[(size_t)(vd + i * 16) * 2048 + nb + vks];
      }
    }

    __builtin_amdgcn_s_setprio(1);
#pragma unroll
    for (int kc = 0; kc < 4; kc++) {
      // S^T[k][q] = K . Q^T : col = q = l31; row k = (r&3)+8*(r>>2)+4*hh
      f32x16 s;
#pragma unroll
      for (int r = 0; r < 16; r++) s[r] = 0.0f;
#pragma unroll
      for (int dseg = 0; dseg < 4; dseg++) {
        const int key = kc * 32 + l31;
        const int krow = key & 63;
        const int cb = ((key >> 6) << 6) + dseg * 16 + hh * 8;
        const bf16x8 kf = *(const bf16x8*)
            &Ks[krow * 128 + (cb ^ ((krow & 15) << 3))];
        s = __builtin_amdgcn_mfma_f32_32x32x16_bf16(kf, qf[dseg], s, 0, 0, 0);
      }
      // raw v_exp_f32 (= 2^x; Q pre-scaled by 1/ln2)
#pragma unroll
      for (int r = 0; r < 16; r++) s[r] = __builtin_amdgcn_exp2f(s[r]);
      // pack consecutive-k pairs: p[i] covers k = {2i, 2i+1} of lane's k-set
      unsigned p[8];
#pragma unroll
      for (int i = 0; i < 8; i++) {
        const float lo = s[2 * i], hi = s[2 * i + 1];
        unsigned d;
        asm("v_cvt_pk_bf16_f32 %0, %1, %2" : "=v"(d) : "v"(lo), "v"(hi));
        p[i] = d;
      }
      // half-swap (x-hi <-> y-lo); s_nop closes the asm-opaque VALU->MFMA
      // hazard window (R11-proven).
      asm("v_permlane32_swap_b32 %0, %1\n\t"
          "v_permlane32_swap_b32 %2, %3\n\t"
          "v_permlane32_swap_b32 %4, %5\n\t"
          "v_permlane32_swap_b32 %6, %7\n\t"
          "s_nop 2"
          : "+v"(p[0]), "+v"(p[2]), "+v"(p[1]), "+v"(p[3]),
            "+v"(p[4]), "+v"(p[6]), "+v"(p[5]), "+v"(p[7]));
#pragma unroll
      for (int kk = 0; kk < 2; kk++) {
        union { unsigned u[4]; bf16x8 v; } pa;
        pa.u[0] = p[kk * 4 + 0];
        pa.u[1] = p[kk * 4 + 1];
        pa.u[2] = p[kk * 4 + 2];
        pa.u[3] = p[kk * 4 + 3];
        const int vcb = (kc * 2 + kk) * 16 + hh * 8;
        const bf16x8 vf0 = *(const bf16x8*)
            &Vs[l31 * 128 + (vcb ^ ((l31 & 15) << 3))];
        const bf16x8 vf1 = *(const bf16x8*)
            &Vs[(32 + l31) * 128 + (vcb ^ ((l31 & 15) << 3))];
        O[0] = __builtin_amdgcn_mfma_f32_32x32x16_bf16(pa.v, vf0, O[0], 0, 0, 0);
        O[1] = __builtin_amdgcn_mfma_f32_32x32x16_bf16(pa.v, vf1, O[1], 0, 0, 0);
        // row sums on the MFMA pipe, placed last: pa long-since readable
        lacc = __builtin_amdgcn_mfma_f32_32x32x16_bf16(pa.v, ones, lacc, 0, 0, 0);
      }
    }
    __builtin_amdgcn_s_setprio(0);
  }

  // lacc C-layout == O C-layout: lacc[r] = l[qrow(r)] on every lane.
  const int bq = bh >> 4, head = bh & 15;
  const size_t rowbase = (size_t)bq * 2048 + q0 + wave * 32;
#pragma unroll
  for (int r = 0; r < 16; r++) {
    const int qrow = (r & 3) + 8 * (r >> 2) + 4 * hh;  // C-layout row
    const float inv = 1.0f / lacc[r];
#pragma unroll
    for (int t = 0; t < 2; t++)
      Ctx[(rowbase + qrow) * 1024 + head * 64 + t * 32 + l31] =
          (short)f2bf(O[t][r] * inv);
  }
}

// ===========================================================================
extern "C" void kernel_launch(void* const* d_in, const int* in_sizes, int n_in,
                              void* d_out, int out_size, void* d_ws, size_t ws_size,
                              hipStream_t stream) {
  const float* queries = (const float*)d_in[0];
  const float* keys    = (const float*)d_in[1];
  const float* values  = (const float*)d_in[2];
  const float* Wq = (const float*)d_in[3];
  const float* bq = (const float*)d_in[4];
  const float* Wk = (const float*)d_in[5];
  const float* bk = (const float*)d_in[6];
  const float* Wv = (const float*)d_in[7];
  const float* bv = (const float*)d_in[8];
  const float* Wo = (const float*)d_in[9];
  const float* bo = (const float*)d_in[10];
  float* out = (float*)d_out;

  const size_t PLANE = (size_t)8192 * 1024 * 2;  // 16 MB (bf16 plane)
  const size_t WPL = (size_t)1024 * 1024 * 2;

  char* p = (char*)d_ws;
  short* WT  = (short*)p;  p += 4 * WPL;    // WqT,WkT,WvT,WoT (8 MB)
  short* X   = (short*)p;  p += 3 * PLANE;  // Xq,Xk,Xv bf16 (48 MB)
  short* Qp  = (short*)p;  p += PLANE;      // Qp,Kp,Vt contiguous (proj3 Obase)
  short* Kp  = (short*)p;  p += PLANE;
  short* Vt  = (short*)p;  p += PLANE;
  short* ctx = X;  // alias: X planes dead after proj3_k; ctx born after attn5_k
  (void)Kp;

  const dim3 blk(256);
  wt4_k<<<dim3(16, 16, 4), blk, 0, stream>>>(Wq, Wk, Wv, Wo, WT);
  cvt3_k<<<dim3(1024, 3), blk, 0, stream>>>(queries, keys, values, X);

  proj3_k<<<dim3(64, 8, 3), blk, 0, stream>>>(X, WT, bq, bk, bv, Qp);

  attn5_k<<<dim3(64, 16), blk, 0, stream>>>(Qp, Kp, Vt, ctx);

  outproj_k<<<dim3(64, 8), blk, 0, stream>>>(ctx, WT + 3 * 1048576, bo, out);
}

// Round 9
// 343.722 us; speedup vs baseline: 1.0929x; 1.0929x over previous
//
#include <hip/hip_runtime.h>
#include <math.h>

// B=4, L=2048, D=1024, H=16, dh=64, M=8192, scale=0.125
// R15: recover from R14's spill regression. attn5's KVBLK=128 reg-prefetch
// exceeded the 128-VGPR cap of launch_bounds(256,4) -> scratch spill
// (WRITE_SIZE 103MB on a 16MB-output kernel). Revert to R13's attn4_k
// (proven 84us) + add T5 setprio(1) around the compute phase (zero register
// cost, attn-proven +4-7% m191). outproj: launch_bounds (256,2)->(256,4)
// (VGPR ~110 fits 128 cap; 4 blocks/CU hides the vmcnt(0) drains).

using f32x4 = __attribute__((ext_vector_type(4))) float;
using f32x16 = __attribute__((ext_vector_type(16))) float;
using bf16x8 = __attribute__((ext_vector_type(8))) short;

__device__ __forceinline__ unsigned short f2bf(float x) {
  union { float f; unsigned u; } v; v.f = x;
  unsigned r = v.u + 0x7fff + ((v.u >> 16) & 1);  // RNE
  return (unsigned short)(r >> 16);
}

__device__ __forceinline__ void g2l16(const void* g, void* l) {
  __builtin_amdgcn_global_load_lds(
      (const __attribute__((address_space(1))) unsigned int*)g,
      (__attribute__((address_space(3))) unsigned int*)l, 16, 0, 0);
}

// Transpose 4 weights in one launch: W[1024 k][1024 n] fp32 -> WT[n][k] bf16
__global__ __launch_bounds__(256) void wt4_k(const float* __restrict__ W0,
                                             const float* __restrict__ W1,
                                             const float* __restrict__ W2,
                                             const float* __restrict__ W3,
                                             short* __restrict__ WT) {
  __shared__ float t[64][65];
  const int z = blockIdx.z;
  const float* W = z == 0 ? W0 : (z == 1 ? W1 : (z == 2 ? W2 : W3));
  short* hiT = WT + (size_t)z * 1048576;
  const int n0 = blockIdx.x * 64, k0 = blockIdx.y * 64;
  const int tid = threadIdx.x;
  const int r = tid >> 4, c4 = (tid & 15) * 4;
#pragma unroll
  for (int i = 0; i < 4; i++) {
    const int row = r + i * 16;  // k
    const float4 v = *(const float4*)&W[(size_t)(k0 + row) * 1024 + n0 + c4];
    t[c4 + 0][row] = v.x;
    t[c4 + 1][row] = v.y;
    t[c4 + 2][row] = v.z;
    t[c4 + 3][row] = v.w;
  }
  __syncthreads();
#pragma unroll
  for (int i = 0; i < 4; i++) {
    const int row = r + i * 16;  // n
    short4 h;
    h.x = (short)f2bf(t[row][c4 + 0]);
    h.y = (short)f2bf(t[row][c4 + 1]);
    h.z = (short)f2bf(t[row][c4 + 2]);
    h.w = (short)f2bf(t[row][c4 + 3]);
    *(short4*)&hiT[(size_t)(n0 + row) * 1024 + k0 + c4] = h;
  }
}

// One-shot fp32 -> bf16 of the three input planes [8192][1024].
__global__ __launch_bounds__(256) void cvt3_k(const float* __restrict__ A0,
                                              const float* __restrict__ A1,
                                              const float* __restrict__ A2,
                                              short* __restrict__ X) {
  const int z = blockIdx.y;
  const float* A = z == 0 ? A0 : (z == 1 ? A1 : A2);
  short* Xo = X + (size_t)z * 8388608;
  const int t0 = blockIdx.x * 256 + threadIdx.x;
#pragma unroll 2
  for (int i = t0; i < 1048576; i += 262144) {
    const size_t o = (size_t)i * 8;
    const float4 a = *(const float4*)&A[o];
    const float4 b = *(const float4*)&A[o + 4];
    short tmp[8];
    tmp[0] = (short)f2bf(a.x);
    tmp[1] = (short)f2bf(a.y);
    tmp[2] = (short)f2bf(a.z);
    tmp[3] = (short)f2bf(a.w);
    tmp[4] = (short)f2bf(b.x);
    tmp[5] = (short)f2bf(b.y);
    tmp[6] = (short)f2bf(b.z);
    tmp[7] = (short)f2bf(b.w);
    *(bf16x8*)&Xo[o] = *(const bf16x8*)tmp;
  }
}

// z-batched projection GEMM: for z in {0,1,2}: C_z = X_z @ WT_z^T + b_z.
// BK=64, source-swizzled g2l16 staging (linear LDS dest, XOR'd global col).
// z=0: Q (x0.125/ln2 for exp2 softmax, bf16 BHLd)  z=1: K  z=2: V [B,H,64,L].
__global__ __launch_bounds__(256, 4) void proj3_k(
    const short* __restrict__ X, const short* __restrict__ WT,
    const float* __restrict__ b0, const float* __restrict__ b1,
    const float* __restrict__ b2, short* __restrict__ Obase) {
  __shared__ short smem[128 * 128];  // As[0..8192) Bs[8192..16384); epi reuse
  short* As = smem;
  short* Bs = smem + 8192;

  const int z = blockIdx.z;
  const short* A_g = X + (size_t)z * 8388608;
  const short* B_g = WT + (size_t)z * 1048576;
  const float* bias = z == 0 ? b0 : (z == 1 ? b1 : b2);
  short* outp = Obase + (size_t)z * 8388608;

  const int tid = threadIdx.x;
  const int lane = tid & 63;
  const int wave = tid >> 6;
  const int quad = lane >> 4;
  const int l16 = lane & 15;
  const int m0 = blockIdx.x * 128;
  const int n0 = blockIdx.y * 128;
  const int wm = (wave >> 1) * 64;
  const int wn = (wave & 1) * 64;

  const int srow = tid >> 3;       // 0..31 (+i*32): 32 rows per issue
  const int soff = (tid & 7) * 8;  // 16B granule within the 128B row

  f32x4 acc[4][4];
#pragma unroll
  for (int i = 0; i < 4; i++)
#pragma unroll
    for (int j = 0; j < 4; j++) acc[i][j] = f32x4{0.f, 0.f, 0.f, 0.f};

  for (int k0 = 0; k0 < 1024; k0 += 64) {
    __syncthreads();
#pragma unroll
    for (int i = 0; i < 4; i++) {
      const int row = srow + i * 32;
      const int osw = soff ^ ((row & 7) << 3);  // inverse-swizzled source col
      g2l16(&A_g[(size_t)(m0 + row) * 1024 + k0 + osw], &As[row * 64 + soff]);
      g2l16(&B_g[(size_t)(n0 + row) * 1024 + k0 + osw], &Bs[row * 64 + soff]);
    }
    __syncthreads();

#pragma unroll
    for (int ks = 0; ks < 2; ks++) {
      bf16x8 ah[4], bh[4];
#pragma unroll
      for (int t = 0; t < 4; t++) {
        const int ar = wm + t * 16 + l16;
        const int br = wn + t * 16 + l16;
        ah[t] = *(const bf16x8*)&As[ar * 64 + ((ks * 32 + quad * 8) ^ ((ar & 7) << 3))];
        bh[t] = *(const bf16x8*)&Bs[br * 64 + ((ks * 32 + quad * 8) ^ ((br & 7) << 3))];
      }
#pragma unroll
      for (int tm = 0; tm < 4; tm++)
#pragma unroll
        for (int tn = 0; tn < 4; tn++)
          acc[tm][tn] = __builtin_amdgcn_mfma_f32_16x16x32_bf16(ah[tm], bh[tn], acc[tm][tn], 0, 0, 0);
    }
  }

  float bz[4];
#pragma unroll
  for (int tn = 0; tn < 4; tn++) bz[tn] = bias[n0 + wn + tn * 16 + l16];
  // Q scale = 0.125 * (1/ln2) so attn can use exp2 directly
  const float sc = (z == 0) ? 0.18033688011112f : 1.0f;

  const int b = m0 >> 11;
  const int lbase = m0 & 2047;

  if (z == 2) {
    // V: [B,H,64,L] via LDS transpose (pad 144), b128 stores along L
#pragma unroll
    for (int half = 0; half < 2; half++) {
      __syncthreads();
      if ((wave & 1) == half) {
#pragma unroll
        for (int tm = 0; tm < 4; tm++)
#pragma unroll
          for (int tn = 0; tn < 4; tn++)
#pragma unroll
            for (int r = 0; r < 4; r++) {
              const int nl = tn * 16 + l16;                // d 0..63
              const int ml = wm + tm * 16 + quad * 4 + r;  // l 0..127
              smem[nl * 144 + ml] = (short)f2bf(acc[tm][tn][r] + bz[tn]);
            }
      }
      __syncthreads();
      const int h = (n0 >> 6) + half;
#pragma unroll
      for (int j = 0; j < 4; j++) {
        const int c = tid + j * 256;
        const int d = c >> 4;
        const int mo = (c & 15) * 8;
        *(bf16x8*)&outp[((size_t)((b * 16 + h) * 64 + d)) * 2048 + lbase + mo] =
            *(const bf16x8*)&smem[d * 144 + mo];
      }
    }
  } else {
    // Q/K: BHLd via LDS bounce (row-major m x 64d, pad 72), b128 stores along d
#pragma unroll
    for (int half = 0; half < 2; half++) {
      __syncthreads();
      if ((wave & 1) == half) {
#pragma unroll
        for (int tm = 0; tm < 4; tm++)
#pragma unroll
          for (int tn = 0; tn < 4; tn++)
#pragma unroll
            for (int r = 0; r < 4; r++) {
              const int ml = wm + tm * 16 + quad * 4 + r;  // 0..127
              const int nl = tn * 16 + l16;                // d 0..63
              smem[ml * 72 + nl] = (short)f2bf((acc[tm][tn][r] + bz[tn]) * sc);
            }
      }
      __syncthreads();
      const int h = (n0 >> 6) + half;
#pragma unroll
      for (int j = 0; j < 4; j++) {
        const int c = tid + j * 256;
        const int ml = c >> 3;          // 0..127
        const int off = (c & 7) * 8;    // 0..56
        *(bf16x8*)&outp[((size_t)(b * 16 + h) * 2048 + lbase + ml) * 64 + off] =
            *(const bf16x8*)&smem[ml * 72 + off];
      }
    }
  }
}

// Output projection: C[8192,1024] fp32 = ctx(bf16) @ WoT^T + bo.
// BK=64, source-swizzled g2l16 staging; (256,4) for drain-hiding occupancy.
__global__ __launch_bounds__(256, 4) void outproj_k(
    const short* __restrict__ A_g, const short* __restrict__ B_g,
    const float* __restrict__ bias, float* __restrict__ out0) {
  __shared__ short As[8192];
  __shared__ short Bs[8192];

  const int tid = threadIdx.x;
  const int lane = tid & 63;
  const int wave = tid >> 6;
  const int quad = lane >> 4;
  const int l16 = lane & 15;
  const int m0 = blockIdx.x * 128;
  const int n0 = blockIdx.y * 128;
  const int wm = (wave >> 1) * 64;
  const int wn = (wave & 1) * 64;
  const int srow = tid >> 3;
  const int soff = (tid & 7) * 8;

  f32x4 acc[4][4];
#pragma unroll
  for (int i = 0; i < 4; i++)
#pragma unroll
    for (int j = 0; j < 4; j++) acc[i][j] = f32x4{0.f, 0.f, 0.f, 0.f};

  for (int k0 = 0; k0 < 1024; k0 += 64) {
    __syncthreads();
#pragma unroll
    for (int i = 0; i < 4; i++) {
      const int row = srow + i * 32;
      const int osw = soff ^ ((row & 7) << 3);
      g2l16(&A_g[(size_t)(m0 + row) * 1024 + k0 + osw], &As[row * 64 + soff]);
      g2l16(&B_g[(size_t)(n0 + row) * 1024 + k0 + osw], &Bs[row * 64 + soff]);
    }
    __syncthreads();

#pragma unroll
    for (int ks = 0; ks < 2; ks++) {
      bf16x8 ah[4], bh[4];
#pragma unroll
      for (int t = 0; t < 4; t++) {
        const int ar = wm + t * 16 + l16;
        const int br = wn + t * 16 + l16;
        ah[t] = *(const bf16x8*)&As[ar * 64 + ((ks * 32 + quad * 8) ^ ((ar & 7) << 3))];
        bh[t] = *(const bf16x8*)&Bs[br * 64 + ((ks * 32 + quad * 8) ^ ((br & 7) << 3))];
      }
#pragma unroll
      for (int tm = 0; tm < 4; tm++)
#pragma unroll
        for (int tn = 0; tn < 4; tn++)
          acc[tm][tn] = __builtin_amdgcn_mfma_f32_16x16x32_bf16(ah[tm], bh[tn], acc[tm][tn], 0, 0, 0);
    }
  }

  float bz[4];
#pragma unroll
  for (int tn = 0; tn < 4; tn++) bz[tn] = bias[n0 + wn + tn * 16 + l16];

#pragma unroll
  for (int tm = 0; tm < 4; tm++)
#pragma unroll
    for (int tn = 0; tn < 4; tn++) {
      const int n = n0 + wn + tn * 16 + l16;
#pragma unroll
      for (int r = 0; r < 4; r++) {
        const int m = m0 + wm + tm * 16 + quad * 4 + r;
        out0[(size_t)m * 1024 + n] = acc[tm][tn][r] + bz[tn];
      }
    }
}

// Flash attention, 32x32x16 MFMA, swapped QK^T, in-register softmax.
// KVBLK=64 (R13-proven, no spill). Block = (b,h) x 128 Q rows (4 waves x 32).
// Grid (bh, qb): XCD-local K/V. Q pre-scaled by 0.125/ln2 -> raw v_exp_f32.
// Row sums on the MFMA pipe. T5 setprio(1) wraps the compute phase.
__global__ __launch_bounds__(256, 4) void attn4_k(const short* __restrict__ Qp,
                                                  const short* __restrict__ Kp,
                                                  const short* __restrict__ Vt,
                                                  short* __restrict__ Ctx) {
  __shared__ short Ks[64 * 64];  // [key][d], XOR-swizzled rows (stride 64)
  __shared__ short Vs[64 * 64];  // [d][key], XOR-swizzled rows

  const int tid = threadIdx.x;
  const int lane = tid & 63;
  const int wave = tid >> 6;
  const int l31 = lane & 31;
  const int hh = lane >> 5;        // wave half
  const int bh = blockIdx.x;       // XCD-local K/V
  const int q0 = blockIdx.y * 128;

  const short* Kb = Kp + (size_t)bh * 2048 * 64;
  const short* Vb = Vt + (size_t)bh * 64 * 2048;

  // Q fragments (B-operand: col q=l31, k-dim d = dseg*16 + hh*8 + e)
  bf16x8 qf[4];
#pragma unroll
  for (int dseg = 0; dseg < 4; dseg++)
    qf[dseg] = *(const bf16x8*)
        &Qp[((size_t)bh * 2048 + q0 + wave * 32 + l31) * 64 + dseg * 16 + hh * 8];

  bf16x8 ones;
#pragma unroll
  for (int j = 0; j < 8; j++) ones[j] = (short)0x3F80;

  f32x16 O[2], lacc;
#pragma unroll
  for (int t = 0; t < 2; t++)
#pragma unroll
    for (int r = 0; r < 16; r++) O[t][r] = 0.0f;
#pragma unroll
  for (int r = 0; r < 16; r++) lacc[r] = 0.0f;

  // staging: 4 x b128 per thread per tile, conflict-free via XOR swizzle
  const int srow0 = tid >> 3;          // 0..31
  const int srow1 = srow0 + 32;        // 32..63
  const int scol = (tid & 7) * 8;      // shorts
  const int w0 = srow0 * 64 + (scol ^ ((srow0 & 7) << 3));
  const int w1 = srow1 * 64 + (scol ^ ((srow1 & 7) << 3));

  bf16x8 kreg[2], vreg[2];
  kreg[0] = *(const bf16x8*)&Kb[(size_t)srow0 * 64 + scol];
  kreg[1] = *(const bf16x8*)&Kb[(size_t)srow1 * 64 + scol];
  vreg[0] = *(const bf16x8*)&Vb[(size_t)srow0 * 2048 + scol];
  vreg[1] = *(const bf16x8*)&Vb[(size_t)srow1 * 2048 + scol];

  for (int kt = 0; kt < 32; kt++) {
    __syncthreads();
    *(bf16x8*)&Ks[w0] = kreg[0];
    *(bf16x8*)&Ks[w1] = kreg[1];
    *(bf16x8*)&Vs[w0] = vreg[0];
    *(bf16x8*)&Vs[w1] = vreg[1];
    __syncthreads();

    if (kt < 31) {  // prefetch next K/V tile (overlaps compute)
      const int nb = (kt + 1) * 64;
      kreg[0] = *(const bf16x8*)&Kb[(size_t)(nb + srow0) * 64 + scol];
      kreg[1] = *(const bf16x8*)&Kb[(size_t)(nb + srow1) * 64 + scol];
      vreg[0] = *(const bf16x8*)&Vb[(size_t)srow0 * 2048 + nb + scol];
      vreg[1] = *(const bf16x8*)&Vb[(size_t)srow1 * 2048 + nb + scol];
    }

    __builtin_amdgcn_s_setprio(1);
#pragma unroll
    for (int kc = 0; kc < 2; kc++) {
      // S^T[k][q] = K . Q^T : col = q = l31; row k = (r&3)+8*(r>>2)+4*hh
      f32x16 s;
#pragma unroll
      for (int r = 0; r < 16; r++) s[r] = 0.0f;
#pragma unroll
      for (int dseg = 0; dseg < 4; dseg++) {
        const int kr = kc * 32 + l31;
        const bf16x8 kf = *(const bf16x8*)
            &Ks[kr * 64 + ((dseg * 16 + hh * 8) ^ ((kr & 7) << 3))];
        s = __builtin_amdgcn_mfma_f32_32x32x16_bf16(kf, qf[dseg], s, 0, 0, 0);
      }
      // raw v_exp_f32 (= 2^x; Q pre-scaled by 1/ln2)
#pragma unroll
      for (int r = 0; r < 16; r++) s[r] = __builtin_amdgcn_exp2f(s[r]);
      // pack consecutive-k pairs: p[i] covers k = {2i, 2i+1} of lane's k-set
      unsigned p[8];
#pragma unroll
      for (int i = 0; i < 8; i++) {
        const float lo = s[2 * i], hi = s[2 * i + 1];
        unsigned d;
        asm("v_cvt_pk_bf16_f32 %0, %1, %2" : "=v"(d) : "v"(lo), "v"(hi));
        p[i] = d;
      }
      // half-swap (x-hi <-> y-lo); s_nop closes the asm-opaque VALU->MFMA
      // hazard window (R11-proven).
      asm("v_permlane32_swap_b32 %0, %1\n\t"
          "v_permlane32_swap_b32 %2, %3\n\t"
          "v_permlane32_swap_b32 %4, %5\n\t"
          "v_permlane32_swap_b32 %6, %7\n\t"
          "s_nop 2"
          : "+v"(p[0]), "+v"(p[2]), "+v"(p[1]), "+v"(p[3]),
            "+v"(p[4]), "+v"(p[6]), "+v"(p[5]), "+v"(p[7]));
#pragma unroll
      for (int kk = 0; kk < 2; kk++) {
        union { unsigned u[4]; bf16x8 v; } pa;
        pa.u[0] = p[kk * 4 + 0];
        pa.u[1] = p[kk * 4 + 1];
        pa.u[2] = p[kk * 4 + 2];
        pa.u[3] = p[kk * 4 + 3];
        const bf16x8 vf0 = *(const bf16x8*)
            &Vs[(0 * 32 + l31) * 64 + ((((kc * 2 + kk) * 16) + hh * 8) ^ ((l31 & 7) << 3))];
        const bf16x8 vf1 = *(const bf16x8*)
            &Vs[(32 + l31) * 64 + ((((kc * 2 + kk) * 16) + hh * 8) ^ ((l31 & 7) << 3))];
        O[0] = __builtin_amdgcn_mfma_f32_32x32x16_bf16(pa.v, vf0, O[0], 0, 0, 0);
        O[1] = __builtin_amdgcn_mfma_f32_32x32x16_bf16(pa.v, vf1, O[1], 0, 0, 0);
        // row sums on the MFMA pipe, placed last: pa long-since readable
        lacc = __builtin_amdgcn_mfma_f32_32x32x16_bf16(pa.v, ones, lacc, 0, 0, 0);
      }
    }
    __builtin_amdgcn_s_setprio(0);
  }

  // lacc C-layout == O C-layout: lacc[r] = l[qrow(r)] on every lane.
  const int bq = bh >> 4, head = bh & 15;
  const size_t rowbase = (size_t)bq * 2048 + q0 + wave * 32;
#pragma unroll
  for (int r = 0; r < 16; r++) {
    const int qrow = (r & 3) + 8 * (r >> 2) + 4 * hh;  // C-layout row
    const float inv = 1.0f / lacc[r];
#pragma unroll
    for (int t = 0; t < 2; t++)
      Ctx[(rowbase + qrow) * 1024 + head * 64 + t * 32 + l31] =
          (short)f2bf(O[t][r] * inv);
  }
}

// ===========================================================================
extern "C" void kernel_launch(void* const* d_in, const int* in_sizes, int n_in,
                              void* d_out, int out_size, void* d_ws, size_t ws_size,
                              hipStream_t stream) {
  const float* queries = (const float*)d_in[0];
  const float* keys    = (const float*)d_in[1];
  const float* values  = (const float*)d_in[2];
  const float* Wq = (const float*)d_in[3];
  const float* bq = (const float*)d_in[4];
  const float* Wk = (const float*)d_in[5];
  const float* bk = (const float*)d_in[6];
  const float* Wv = (const float*)d_in[7];
  const float* bv = (const float*)d_in[8];
  const float* Wo = (const float*)d_in[9];
  const float* bo = (const float*)d_in[10];
  float* out = (float*)d_out;

  const size_t PLANE = (size_t)8192 * 1024 * 2;  // 16 MB (bf16 plane)
  const size_t WPL = (size_t)1024 * 1024 * 2;

  char* p = (char*)d_ws;
  short* WT  = (short*)p;  p += 4 * WPL;    // WqT,WkT,WvT,WoT (8 MB)
  short* X   = (short*)p;  p += 3 * PLANE;  // Xq,Xk,Xv bf16 (48 MB)
  short* Qp  = (short*)p;  p += PLANE;      // Qp,Kp,Vt contiguous (proj3 Obase)
  short* Kp  = (short*)p;  p += PLANE;
  short* Vt  = (short*)p;  p += PLANE;
  short* ctx = X;  // alias: X planes dead after proj3_k; ctx born after attn4_k
  (void)Kp;

  const dim3 blk(256);
  wt4_k<<<dim3(16, 16, 4), blk, 0, stream>>>(Wq, Wk, Wv, Wo, WT);
  cvt3_k<<<dim3(1024, 3), blk, 0, stream>>>(queries, keys, values, X);

  proj3_k<<<dim3(64, 8, 3), blk, 0, stream>>>(X, WT, bq, bk, bv, Qp);

  attn4_k<<<dim3(64, 16), blk, 0, stream>>>(Qp, Kp, Vt, ctx);

  outproj_k<<<dim3(64, 8), blk, 0, stream>>>(ctx, WT + 3 * 1048576, bo, out);
}